// Round 8
// baseline (684.147 us; speedup 1.0000x reference)
//
#include <hip/hip_runtime.h>

typedef __attribute__((ext_vector_type(8))) short short8;
typedef __attribute__((ext_vector_type(4))) float f32x4;
typedef unsigned short ushort_t;
typedef unsigned int u32;
typedef unsigned long long u64;

#define MFMA16(a,b,c) __builtin_amdgcn_mfma_f32_16x16x32_bf16((a),(b),(c),0,0,0)

__device__ __forceinline__ ushort_t f2bf(float f){
  union { float f; u32 u; } v; v.f = f;
  u32 r = v.u + 0x7fffu + ((v.u >> 16) & 1u);
  return (ushort_t)(r >> 16);
}
__device__ __forceinline__ float bf2f(ushort_t h){
  union { u32 u; float f; } v; v.u = ((u32)h) << 16; return v.f;
}
__device__ __forceinline__ u64 pack4(float a, float b, float c, float d){
  u32 p0 = (u32)f2bf(a) | ((u32)f2bf(b) << 16);
  u32 p1 = (u32)f2bf(c) | ((u32)f2bf(d) << 16);
  return (u64)p0 | ((u64)p1 << 32);
}
__device__ __forceinline__ u32 pack2(float a, float b){
  return (u32)f2bf(a) | ((u32)f2bf(b) << 16);
}

template<int CTRL>
__device__ __forceinline__ float dpp_add(float x){
  union { float f; int i; } a, b;
  a.f = x;
  b.i = __builtin_amdgcn_update_dpp(a.i, a.i, CTRL, 0xF, 0xF, false);
  return x + b.f;
}
__device__ __forceinline__ float red4_add(float x){
  x = dpp_add<0xB1>(x); x = dpp_add<0x4E>(x);
  return x;
}

// B=4096 T=32 C=180 H=6 HD=30 ; tokens=131072
// ws (ushort): wqkv[6][3][32][192] | w1t[768][192] | w2t[192][768]
#define WQKV_ELEMS (576*192)
#define W1T_ELEMS  (768*192)
#define W2T_ELEMS  (192*768)

#define SH 200   // 400B rows (192 cols + pad)
#define SS 36    // 72B scratch rows: 18 words, 18t mod 32 distinct for t<16 -> ~conflict-free

// ---- prep: LDS-tiled coalesced transposes (runs once, 42 blocks)
__global__ void prep_weights(const float* __restrict__ wq, const float* __restrict__ wk,
                             const float* __restrict__ wv, const float* __restrict__ w1,
                             const float* __restrict__ w2, ushort_t* __restrict__ ws){
  __shared__ float lds_f[11700];
  ushort_t* wqkv = ws;
  ushort_t* w1t = ws + WQKV_ELEMS;
  ushort_t* w2t = w1t + W1T_ELEMS;
  int bid = blockIdx.x, tid = threadIdx.x;

  if (bid < 18){
    int h = bid / 3, m = bid % 3;
    const float* src = ((m == 0) ? wq : (m == 1) ? wk : wv) + (size_t)h*180*30;
    for (int l = 0; l < 22; l++){
      int idx = tid + l*256;
      if (idx < 5400) lds_f[idx] = src[idx];
    }
    __syncthreads();
    u32* dst = (u32*)wqkv;
    for (int l = 0; l < 12; l++){
      int j = tid + l*256;
      int d = j / 96, kp = j - d*96;
      int k0 = 2*kp;
      float f0 = (d < 30 && k0   < 180) ? lds_f[k0*30 + d]     : 0.f;
      float f1 = (d < 30 && k0+1 < 180) ? lds_f[(k0+1)*30 + d] : 0.f;
      dst[(size_t)(h*96 + m*32 + d)*96 + kp] = pack2(f0, f1);
    }
  } else if (bid < 30){
    int n0 = (bid - 18) * 64;
    for (int l = 0; l < 45; l++){
      int idx = tid + l*256;
      int c = idx >> 6, nl = idx & 63;
      int n = n0 + nl;
      lds_f[nl*180 + c] = (n < 720) ? w1[(size_t)c*720 + n] : 0.f;
    }
    __syncthreads();
    u32* dst = (u32*)w1t;
    for (int l = 0; l < 24; l++){
      int j = tid + l*256;
      int nl = j / 96, cp = j - nl*96;
      int c0 = 2*cp;
      float f0 = (c0   < 180) ? lds_f[nl*180 + c0]     : 0.f;
      float f1 = (c0+1 < 180) ? lds_f[nl*180 + c0 + 1] : 0.f;
      dst[(size_t)(n0 + nl)*96 + cp] = pack2(f0, f1);
    }
  } else {
    int c40 = (bid - 30) * 64;
    for (int l = 0; l < 45; l++){
      int idx = tid + l*256;
      int c4l = idx / 180, no = idx - c4l*180;
      lds_f[no*65 + c4l] = (c40 + c4l < 720) ? w2[(size_t)(c40 + c4l)*180 + no] : 0.f;
    }
    __syncthreads();
    u32* dst = (u32*)w2t;
    for (int l = 0; l < 24; l++){
      int j = tid + l*256;
      int no = j >> 5, cp = j & 31;
      float f0 = (no < 180) ? lds_f[no*65 + 2*cp]     : 0.f;
      float f1 = (no < 180) ? lds_f[no*65 + 2*cp + 1] : 0.f;
      dst[(size_t)no*384 + (c40 >> 1) + cp] = pack2(f0, f1);
    }
  }
}

// ---------------- Fused kernel: 64 tokens/block, EIGHT waves (512 thr), 76.8KB LDS,
// 2 blocks/CU -> 16 waves/CU (4/SIMD). Same per-round work as R4/R7 but split over
// 2x the waves: halves each wave's serial stall chain, doubles SIMD interleave.
// Attention: wave-PAIRS share one scratch slot (each wave does a 16-token half).
// MLP: 8-way tile split + double-buffered act (W and att regions) -> 1 barrier/chunk.
__global__ __launch_bounds__(512, 4)
void block_kernel(const float* __restrict__ x,
                  const float* __restrict__ g1, const float* __restrict__ be1,
                  const float* __restrict__ g2, const float* __restrict__ be2,
                  const float* __restrict__ b1, const float* __restrict__ b2,
                  const ushort_t* __restrict__ wqkv, const ushort_t* __restrict__ w1t,
                  const ushort_t* __restrict__ w2t, float* __restrict__ out){
  __shared__ __align__(16) ushort_t W[64*SH];    // attn scratch -> act buf0
  __shared__ __align__(16) ushort_t hn[64*SH];   // x bf16 -> LN1 -> x2 -> LN2
  __shared__ __align__(16) ushort_t att[64*SH];  // attn out [t][c] -> act buf1

  int tid = threadIdx.x;
  int wave = tid >> 6, lane = tid & 63;
  int quad = lane >> 4, c16 = lane & 15;
  long base = (long)blockIdx.x * 11520;   // 64 tokens * 180

  // ---- stage x -> hn bf16 (pad cols 180..191 zero); 2880 + 192 jobs over 512 thr
  #pragma unroll 1
  for (int it = 0; it < 6; it++){
    int idx = it*512 + tid;
    if (idx < 2880){
      f32x4 v = *(const f32x4*)(x + base + (long)idx*4);
      int row = (int)(((u32)idx * 745655u) >> 25);   // idx/45
      int col = idx - row*45;
      *(u64*)(hn + row*SH + col*4) = pack4(v.x, v.y, v.z, v.w);
    } else {
      int p = idx - 2880;
      int row = (p*21846) >> 16;
      int g = p - row*3;
      *(u64*)(hn + row*SH + 180 + g*4) = 0ull;
    }
  }
  __syncthreads();

  // ---- LN1 in-place on hn: 8 threads/row, 24 cols each (pad zeros included)
  {
    int row = tid >> 3, sub = tid & 7;
    int c0 = sub*24;
    float s1 = 0.f, s2 = 0.f;
    u64 mv[6];
    #pragma unroll
    for (int gi = 0; gi < 6; gi++){
      mv[gi] = *(const u64*)(hn + row*SH + c0 + gi*4);
      #pragma unroll
      for (int e = 0; e < 4; e++){
        float v = bf2f((ushort_t)(mv[gi] >> (16*e)));
        s1 += v; s2 += v*v;
      }
    }
    s1 = red4_add(s1); s1 += __shfl_xor(s1, 4);
    s2 = red4_add(s2); s2 += __shfl_xor(s2, 4);
    float mu = s1 * (1.f/180.f);
    float rstd = rsqrtf(s2 * (1.f/180.f) - mu*mu + 1e-5f);
    #pragma unroll
    for (int gi = 0; gi < 6; gi++){
      int c = c0 + gi*4;
      if (c < 180){
        f32x4 gg = *(const f32x4*)(g1 + c);
        f32x4 bb = *(const f32x4*)(be1 + c);
        float v0 = (bf2f((ushort_t)(mv[gi]    )) - mu)*rstd*gg.x + bb.x;
        float v1 = (bf2f((ushort_t)(mv[gi]>>16)) - mu)*rstd*gg.y + bb.y;
        float v2 = (bf2f((ushort_t)(mv[gi]>>32)) - mu)*rstd*gg.z + bb.z;
        float v3 = (bf2f((ushort_t)(mv[gi]>>48)) - mu)*rstd*gg.w + bb.w;
        *(u64*)(hn + row*SH + c) = pack4(v0, v1, v2, v3);
      }
    }
  }
  __syncthreads();

  // ---- attention: 12 jobs over 4 wave-pairs x 3 rounds; each wave does a 16-token half
  {
    int pair = wave >> 1, half = wave & 1;
    ushort_t* buf0 = W + pair*(2*32*SS);   // q [t][d], then vT [d][s]
    ushort_t* buf1 = buf0 + 32*SS;         // k [t][d], then P [t][s]
    const float scl = 0.18257418583505537f;  // 30^-0.5
    int t = half*16 + c16;                 // this lane's token (within 32-token window)

    #pragma unroll 1
    for (int r3 = 0; r3 < 3; r3++){
      int j = r3*4 + pair;
      int bb = (j >= 6) ? 1 : 0;
      int head = j - 6*bb;
      const ushort_t* wbase = wqkv + head*(96*192);

      f32x4 accq[2], acck[2], accv[2];
      #pragma unroll
      for (int i = 0; i < 2; i++){ accq[i]=(f32x4)0.f; acck[i]=(f32x4)0.f; accv[i]=(f32x4)0.f; }

      #pragma unroll 1
      for (int kk = 0; kk < 6; kk++){
        const ushort_t* wk0 = wbase + c16*192 + kk*32 + quad*8;
        short8 aq0 = *(const short8*)(wk0);
        short8 aq1 = *(const short8*)(wk0 + 16*192);
        short8 ak0 = *(const short8*)(wk0 + 32*192);
        short8 ak1 = *(const short8*)(wk0 + 48*192);
        short8 av0 = *(const short8*)(wk0 + 64*192);
        short8 av1 = *(const short8*)(wk0 + 80*192);
        short8 hf = *(const short8*)(hn + (bb*32 + half*16 + c16)*SH + kk*32 + quad*8);
        accq[0] = MFMA16(aq0, hf, accq[0]);   // C[d][t-own]
        accq[1] = MFMA16(aq1, hf, accq[1]);
        acck[0] = MFMA16(ak0, hf, acck[0]);   // C[d][t-own]
        acck[1] = MFMA16(ak1, hf, acck[1]);
        accv[0] = MFMA16(hf, av0, accv[0]);   // C[s-own][d]
        accv[1] = MFMA16(hf, av1, accv[1]);
      }
      // q,k rowmajor [t][d]: own 16 rows
      #pragma unroll
      for (int mt = 0; mt < 2; mt++){
        *(u64*)(buf0 + t*SS + mt*16 + quad*4) =
          pack4(accq[mt][0], accq[mt][1], accq[mt][2], accq[mt][3]);
        *(u64*)(buf1 + t*SS + mt*16 + quad*4) =
          pack4(acck[mt][0], acck[mt][1], acck[mt][2], acck[mt][3]);
      }
      __syncthreads();   // partner's k-half visible
      // S^T[s][t-own] = MFMA(A=k rows s, B=q rows t-own)
      f32x4 sacc[2];
      sacc[0] = (f32x4)0.f; sacc[1] = (f32x4)0.f;
      short8 akf0 = *(const short8*)(buf1 + c16*SS + quad*8);
      short8 akf1 = *(const short8*)(buf1 + (16 + c16)*SS + quad*8);
      short8 bq   = *(const short8*)(buf0 + t*SS + quad*8);
      sacc[0] = MFMA16(akf0, bq, sacc[0]);
      sacc[1] = MFMA16(akf1, bq, sacc[1]);
      // softmax for token t: 8 s-values in-lane; reduce over quads (xor16,32)
      {
        float v[8];
        #pragma unroll
        for (int r = 0; r < 4; r++){
          int s0 = quad*4 + r, s1v = 16 + quad*4 + r;
          v[r]   = (s0  > t) ? -1e30f : sacc[0][r]*scl;
          v[4+r] = (s1v > t) ? -1e30f : sacc[1][r]*scl;
        }
        float m = v[0];
        #pragma unroll
        for (int i = 1; i < 8; i++) m = fmaxf(m, v[i]);
        m = fmaxf(m, __shfl_xor(m, 16));
        m = fmaxf(m, __shfl_xor(m, 32));
        float e[8], s = 0.f;
        #pragma unroll
        for (int i = 0; i < 8; i++){ e[i] = __expf(v[i] - m); s += e[i]; }
        s += __shfl_xor(s, 16);
        s += __shfl_xor(s, 32);
        float inv = 1.f / s;
        *(u64*)(buf1 + t*SS +      quad*4) = pack4(e[0]*inv, e[1]*inv, e[2]*inv, e[3]*inv);
        *(u64*)(buf1 + t*SS + 16 + quad*4) = pack4(e[4]*inv, e[5]*inv, e[6]*inv, e[7]*inv);
      }
      // vT [d][s]: own s-columns (accv[nt]: row s-own = half*16+quad*4+r, col d = nt*16+c16)
      #pragma unroll
      for (int nt = 0; nt < 2; nt++)
        *(u64*)(buf0 + (nt*16 + c16)*SS + half*16 + quad*4) =
          pack4(accv[nt][0], accv[nt][1], accv[nt][2], accv[nt][3]);
      __syncthreads();   // P + both vT halves visible
      // PV: C[d][t-own] = MFMA(A=vT rows d, B=P rows t-own)
      f32x4 oacc[2];
      oacc[0] = (f32x4)0.f; oacc[1] = (f32x4)0.f;
      short8 avf0 = *(const short8*)(buf0 + c16*SS + quad*8);
      short8 avf1 = *(const short8*)(buf0 + (16 + c16)*SS + quad*8);
      short8 bp   = *(const short8*)(buf1 + t*SS + quad*8);
      oacc[0] = MFMA16(avf0, bp, oacc[0]);
      oacc[1] = MFMA16(avf1, bp, oacc[1]);
      // att[t][head*30+d] u32 pairs (d = mt*16+quad*4+r; drop d>=30)
      #pragma unroll
      for (int mt = 0; mt < 2; mt++){
        ushort_t* p = att + (bb*32 + t)*SH + head*30 + mt*16 + quad*4;
        *(u32*)(p) = pack2(oacc[mt][0], oacc[mt][1]);
        if (mt == 0 || quad < 3)
          *(u32*)(p + 2) = pack2(oacc[mt][2], oacc[mt][3]);
      }
      __syncthreads();   // scratch reusable next round
    }
  }

  // ---- x2 = x + att: fp32 -> out (coalesced), bf16 -> hn
  #pragma unroll 1
  for (int it = 0; it < 6; it++){
    int idx = it*512 + tid;
    if (idx < 2880){
      f32x4 v = *(const f32x4*)(x + base + (long)idx*4);
      int row = (int)(((u32)idx * 745655u) >> 25);
      int col4 = (idx - row*45)*4;
      u64 m = *(const u64*)(att + row*SH + col4);
      v.x += bf2f((ushort_t)(m      ));
      v.y += bf2f((ushort_t)(m >> 16));
      v.z += bf2f((ushort_t)(m >> 32));
      v.w += bf2f((ushort_t)(m >> 48));
      *(f32x4*)(out + base + (long)idx*4) = v;
      *(u64*)(hn + row*SH + col4) = pack4(v.x, v.y, v.z, v.w);
    }
    // pad cols in hn still zero from the stage phase
  }
  __syncthreads();

  // ---- LN2 in-place on hn
  {
    int row = tid >> 3, sub = tid & 7;
    int c0 = sub*24;
    float s1 = 0.f, s2 = 0.f;
    u64 mv[6];
    #pragma unroll
    for (int gi = 0; gi < 6; gi++){
      mv[gi] = *(const u64*)(hn + row*SH + c0 + gi*4);
      #pragma unroll
      for (int e = 0; e < 4; e++){
        float v = bf2f((ushort_t)(mv[gi] >> (16*e)));
        s1 += v; s2 += v*v;
      }
    }
    s1 = red4_add(s1); s1 += __shfl_xor(s1, 4);
    s2 = red4_add(s2); s2 += __shfl_xor(s2, 4);
    float mu = s1 * (1.f/180.f);
    float rstd = rsqrtf(s2 * (1.f/180.f) - mu*mu + 1e-5f);
    #pragma unroll
    for (int gi = 0; gi < 6; gi++){
      int c = c0 + gi*4;
      if (c < 180){
        f32x4 gg = *(const f32x4*)(g2 + c);
        f32x4 bb = *(const f32x4*)(be2 + c);
        float v0 = (bf2f((ushort_t)(mv[gi]    )) - mu)*rstd*gg.x + bb.x;
        float v1 = (bf2f((ushort_t)(mv[gi]>>16)) - mu)*rstd*gg.y + bb.y;
        float v2 = (bf2f((ushort_t)(mv[gi]>>32)) - mu)*rstd*gg.z + bb.z;
        float v3 = (bf2f((ushort_t)(mv[gi]>>48)) - mu)*rstd*gg.w + bb.w;
        *(u64*)(hn + row*SH + c) = pack4(v0, v1, v2, v3);
      }
    }
  }
  __syncthreads();   // also: att region (act buf1) free after x2

  // ---- MLP: 4 chunks; act double-buffered (even ch -> W, odd ch -> att);
  //      8-way tile split; ONE barrier per chunk.
  {
    int wn  = wave >> 1, wt  = wave & 1;   // MLP1: n-group (48 rows), t-group (32 tok)
    int wt2 = wave >> 2, wno = wave & 3;   // MLP2: t-group (32 tok), no-group (48 cols)
    f32x4 outacc[2][3];                    // [t-tile][no-tile], accumulated over ch
    #pragma unroll
    for (int i = 0; i < 2; i++)
      #pragma unroll
      for (int jx = 0; jx < 3; jx++) outacc[i][jx] = (f32x4)0.f;

    #pragma unroll 1
    for (int ch = 0; ch < 4; ch++){
      ushort_t* actb = (ch & 1) ? att : W;
      // MLP1: C[n][t] = MFMA(A=w1 rows n, B=hn rows t)
      f32x4 aacc[3][2];
      #pragma unroll
      for (int i = 0; i < 3; i++){ aacc[i][0]=(f32x4)0.f; aacc[i][1]=(f32x4)0.f; }
      #pragma unroll 1
      for (int kk = 0; kk < 6; kk++){
        const ushort_t* wb = w1t + (size_t)(ch*192 + wn*48 + c16)*192 + kk*32 + quad*8;
        short8 aw0 = *(const short8*)(wb);
        short8 aw1 = *(const short8*)(wb + 16*192);
        short8 aw2 = *(const short8*)(wb + 32*192);
        const ushort_t* hb = hn + (wt*32 + c16)*SH + kk*32 + quad*8;
        short8 bh0 = *(const short8*)(hb);
        short8 bh1 = *(const short8*)(hb + 16*SH);
        aacc[0][0] = MFMA16(aw0, bh0, aacc[0][0]);
        aacc[0][1] = MFMA16(aw0, bh1, aacc[0][1]);
        aacc[1][0] = MFMA16(aw1, bh0, aacc[1][0]);
        aacc[1][1] = MFMA16(aw1, bh1, aacc[1][1]);
        aacc[2][0] = MFMA16(aw2, bh0, aacc[2][0]);
        aacc[2][1] = MFMA16(aw2, bh1, aacc[2][1]);
      }
      // bias + relu + packed store act[t][n] (own t-range, own n-range)
      #pragma unroll
      for (int mi = 0; mi < 3; mi++){
        int nrel = (wn*3+mi)*16 + quad*4;
        int nabs = ch*192 + nrel;
        f32x4 bias = (f32x4)0.f;
        if (nabs < 720) bias = *(const f32x4*)(b1 + nabs);
        #pragma unroll
        for (int tt = 0; tt < 2; tt++){
          float v0 = fmaxf(aacc[mi][tt][0] + bias[0], 0.f);
          float v1 = fmaxf(aacc[mi][tt][1] + bias[1], 0.f);
          float v2 = fmaxf(aacc[mi][tt][2] + bias[2], 0.f);
          float v3 = fmaxf(aacc[mi][tt][3] + bias[3], 0.f);
          *(u64*)(actb + (wt*32 + tt*16 + c16)*SH + nrel) = pack4(v0, v1, v2, v3);
        }
      }
      __syncthreads();   // act[ch&1] fully written (and, transitively, prev MLP2 done)
      // MLP2: C[t][no] += MFMA(A=act rows t, B=w2 rows no)
      #pragma unroll 1
      for (int kk = 0; kk < 6; kk++){
        const ushort_t* wb2 = w2t + (size_t)(wno*48 + c16)*768 + ch*192 + kk*32 + quad*8;
        short8 bw0 = *(const short8*)(wb2);
        short8 bw1 = *(const short8*)(wb2 + 16*768);
        short8 bw2 = *(const short8*)(wb2 + 32*768);
        const ushort_t* ab = actb + (wt2*32 + c16)*SH + kk*32 + quad*8;
        short8 aa0 = *(const short8*)(ab);
        short8 aa1 = *(const short8*)(ab + 16*SH);
        outacc[0][0] = MFMA16(aa0, bw0, outacc[0][0]);
        outacc[0][1] = MFMA16(aa0, bw1, outacc[0][1]);
        outacc[0][2] = MFMA16(aa0, bw2, outacc[0][2]);
        outacc[1][0] = MFMA16(aa1, bw0, outacc[1][0]);
        outacc[1][1] = MFMA16(aa1, bw1, outacc[1][1]);
        outacc[1][2] = MFMA16(aa1, bw2, outacc[1][2]);
      }
    }
    // epilogue: out[t][no] = x2 (already in out) + mlp + b2
    #pragma unroll
    for (int ntl = 0; ntl < 3; ntl++){
      int no = wno*48 + ntl*16 + c16;
      if (no < 180){
        float bias = b2[no];
        #pragma unroll
        for (int tt = 0; tt < 2; tt++){
          #pragma unroll
          for (int r = 0; r < 4; r++){
            long a = base + (long)(wt2*32 + tt*16 + quad*4 + r)*180 + no;
            out[a] = out[a] + outacc[tt][ntl][r] + bias;
          }
        }
      }
    }
  }
}

extern "C" void kernel_launch(void* const* d_in, const int* in_sizes, int n_in,
                              void* d_out, int out_size, void* d_ws, size_t ws_size,
                              hipStream_t stream) {
  const float* x   = (const float*)d_in[0];
  const float* wq  = (const float*)d_in[1];
  const float* wk  = (const float*)d_in[2];
  const float* wv  = (const float*)d_in[3];
  const float* g1  = (const float*)d_in[4];
  const float* be1 = (const float*)d_in[5];
  const float* g2  = (const float*)d_in[6];
  const float* be2 = (const float*)d_in[7];
  const float* w1  = (const float*)d_in[8];
  const float* b1  = (const float*)d_in[9];
  const float* w2  = (const float*)d_in[10];
  const float* b2  = (const float*)d_in[11];
  ushort_t* ws   = (ushort_t*)d_ws;
  ushort_t* wqkv = ws;
  ushort_t* w1t  = ws + WQKV_ELEMS;
  ushort_t* w2t  = w1t + W1T_ELEMS;
  float* out = (float*)d_out;

  prep_weights<<<42, 256, 0, stream>>>(wq, wk, wv, w1, w2, ws);
  block_kernel<<<2048, 512, 0, stream>>>(x, g1, be1, g2, be2, b1, b2,
                                         wqkv, w1t, w2t, out);
}

// Round 10
// 433.045 us; speedup vs baseline: 1.5799x; 1.5799x over previous
//
#include <hip/hip_runtime.h>

typedef __attribute__((ext_vector_type(8))) short short8;
typedef __attribute__((ext_vector_type(4))) float f32x4;
typedef unsigned short ushort_t;
typedef unsigned int u32;
typedef unsigned long long u64;

#define MFMA16(a,b,c) __builtin_amdgcn_mfma_f32_16x16x32_bf16((a),(b),(c),0,0,0)

__device__ __forceinline__ ushort_t f2bf(float f){
  union { float f; u32 u; } v; v.f = f;
  u32 r = v.u + 0x7fffu + ((v.u >> 16) & 1u);
  return (ushort_t)(r >> 16);
}
__device__ __forceinline__ float bf2f(ushort_t h){
  union { u32 u; float f; } v; v.u = ((u32)h) << 16; return v.f;
}
__device__ __forceinline__ u64 pack4(float a, float b, float c, float d){
  u32 p0 = (u32)f2bf(a) | ((u32)f2bf(b) << 16);
  u32 p1 = (u32)f2bf(c) | ((u32)f2bf(d) << 16);
  return (u64)p0 | ((u64)p1 << 32);
}
__device__ __forceinline__ u32 pack2(float a, float b){
  return (u32)f2bf(a) | ((u32)f2bf(b) << 16);
}

template<int CTRL>
__device__ __forceinline__ float dpp_add(float x){
  union { float f; int i; } a, b;
  a.f = x;
  b.i = __builtin_amdgcn_update_dpp(a.i, a.i, CTRL, 0xF, 0xF, false);
  return x + b.f;
}
__device__ __forceinline__ float red4_add(float x){
  x = dpp_add<0xB1>(x); x = dpp_add<0x4E>(x);
  return x;
}

// async global->LDS, 16B per lane; LDS dest = wave-uniform base + lane*16
__device__ __forceinline__ void gll16(const ushort_t* g, ushort_t* l){
  __builtin_amdgcn_global_load_lds(
      (const __attribute__((address_space(1))) void*)g,
      (__attribute__((address_space(3))) void*)l, 16, 0, 0);
}

// counted-vmcnt wait (NO barrier): drains prev slice's 3 loads, keeps next 3 in flight.
// sched_barrier fences stop hipcc hoisting the dependent ds_reads above the wait.
#define WVM(N) do{ \
  __builtin_amdgcn_sched_barrier(0); \
  asm volatile("s_waitcnt vmcnt(" #N ")" ::: "memory"); \
  __builtin_amdgcn_sched_barrier(0); \
}while(0)

// stage one 12KB slice (6144 ushorts): 3 gll16 per wave; each wave stages (and later
// reads) ONLY its own 1536-ushort quarter -> no cross-wave sync needed for weights.
#define STAGE(slice, dbuf) do{ \
  const ushort_t* _s = (slice) + wave*1536 + (lane << 3); \
  ushort_t* _d = (dbuf) + wave*1536; \
  gll16(_s,         _d); \
  gll16(_s + 512,   _d + 512); \
  gll16(_s + 1024,  _d + 1024); \
}while(0)

// B=4096 T=32 C=180 H=6 HD=30 ; tokens=131072
// ws (ushort): wqkv[6][3][32][192] | w1s[24 slices][6144] | w2s[24 slices][6144]
#define WQKV_ELEMS (576*192)
#define W1T_ELEMS  (768*192)
#define W2T_ELEMS  (192*768)

#define SH 200   // 400B rows (192 cols + pad)
#define SS 40    //  80B rows: attn scratch
#define SA 184   // att rows [t][c] c=head*30+d (180 + 4 pad)

// ---- prep: wqkv as before; w1/w2 as 12KB quarter-plane slices.
// Slice (ch,kk) ushort i: j=i>>3, e=i&7; n=((j>>6)<<4)|(j&15); cl=(((j>>4)&3)<<3)|e.
__global__ void prep_weights(const float* __restrict__ wq, const float* __restrict__ wk,
                             const float* __restrict__ wv, const float* __restrict__ w1,
                             const float* __restrict__ w2, ushort_t* __restrict__ ws){
  ushort_t* wqkv = ws;
  ushort_t* w1s = ws + WQKV_ELEMS;
  ushort_t* w2s = w1s + W1T_ELEMS;
  int tid = blockIdx.x * blockDim.x + threadIdx.x;
  int stride = gridDim.x * blockDim.x;
  for (int i = tid; i < WQKV_ELEMS; i += stride){
    int k = i % 192; int row = i / 192;
    int d = row & 31; int m = (row >> 5) % 3; int h = row / 96;
    float v = 0.f;
    if (d < 30 && k < 180){
      const float* W = (m == 0) ? wq : ((m == 1) ? wk : wv);
      v = W[(h*180 + k)*30 + d];
    }
    wqkv[i] = f2bf(v);
  }
  for (int i = tid; i < W1T_ELEMS; i += stride){
    int slice = i / 6144;  int r = i - slice*6144;
    int ch = slice / 6, kk = slice - ch*6;
    int j = r >> 3, e = r & 7;
    int n = ((j >> 6) << 4) | (j & 15);
    int cl = (((j >> 4) & 3) << 3) | e;
    int c = kk*32 + cl;
    int nab = ch*192 + n;
    float v = (nab < 720 && c < 180) ? w1[(size_t)c*720 + nab] : 0.f;
    w1s[i] = f2bf(v);
  }
  for (int i = tid; i < W2T_ELEMS; i += stride){
    int slice = i / 6144;  int r = i - slice*6144;
    int ch = slice / 6, kk = slice - ch*6;
    int j = r >> 3, e = r & 7;
    int n = ((j >> 6) << 4) | (j & 15);
    int cl = (((j >> 4) & 3) << 3) | e;
    int c4 = ch*192 + kk*32 + cl;
    float v = (n < 180 && c4 < 720) ? w2[(size_t)c4*180 + n] : 0.f;
    w2s[i] = f2bf(v);
  }
}

// ---------------- Fused kernel: 64 tokens/block, 4 waves, ~78.7KB LDS, 2 blocks/CU.
// Attention unchanged (R7). MLP weights stream via global_load_lds (sink-proof)
// into a double buffer with counted vmcnt waits; inner kk loops are barrier-free
// (each wave owns its slice quarter); 2 __syncthreads per chunk for act hand-off.
__global__ __launch_bounds__(256, 2)
void block_kernel(const float* __restrict__ x,
                  const float* __restrict__ g1, const float* __restrict__ be1,
                  const float* __restrict__ g2, const float* __restrict__ be2,
                  const float* __restrict__ b1, const float* __restrict__ b2,
                  const ushort_t* __restrict__ wqkv, const ushort_t* __restrict__ w1s,
                  const ushort_t* __restrict__ w2s, float* __restrict__ out){
  __shared__ __align__(16) ushort_t W[64*SH];     // attn scratch -> act
  __shared__ __align__(16) ushort_t hn[64*SH];    // x bf16 -> LN1 -> x2 -> LN2
  __shared__ __align__(16) ushort_t attU[12288];  // att[64][SA]  U  bufS[2][6144]
  __shared__ __align__(16) float biasL[720];      // b1 (keeps MLP loop vmem-free)

  int tid = threadIdx.x;
  int wave = tid >> 6, lane = tid & 63;
  int quad = lane >> 4, c16 = lane & 15;
  long base = (long)blockIdx.x * 11520;   // 64 tokens * 180

  // ---- stage x -> hn bf16 (pad cols 180..191 zero); b1 -> LDS
  if (tid < 180) *(f32x4*)(biasL + (tid << 2)) = *(const f32x4*)(b1 + (tid << 2));
  #pragma unroll 1
  for (int it = 0; it < 12; it++){
    int idx = it*256 + tid;
    if (idx < 2880){
      f32x4 v = *(const f32x4*)(x + base + (long)idx*4);
      int row = (int)(((u32)idx * 745655u) >> 25);   // idx/45
      int col = idx - row*45;
      *(u64*)(hn + row*SH + col*4) = pack4(v.x, v.y, v.z, v.w);
    } else {
      int p = idx - 2880;
      int row = (p*21846) >> 16;
      int g = p - row*3;
      *(u64*)(hn + row*SH + 180 + g*4) = 0ull;
    }
  }
  __syncthreads();

  // ---- LN1 in-place on hn (4 threads/row, 48 cols each)
  {
    int row = tid >> 2, sub = tid & 3;
    int c0 = sub*48;
    float s1 = 0.f, s2 = 0.f;
    u64 mv[12];
    #pragma unroll
    for (int gi = 0; gi < 12; gi++){
      mv[gi] = *(const u64*)(hn + row*SH + c0 + gi*4);
      #pragma unroll
      for (int e = 0; e < 4; e++){
        float v = bf2f((ushort_t)(mv[gi] >> (16*e)));
        s1 += v; s2 += v*v;
      }
    }
    s1 = red4_add(s1); s2 = red4_add(s2);
    float mu = s1 * (1.f/180.f);
    float rstd = rsqrtf(s2 * (1.f/180.f) - mu*mu + 1e-5f);
    #pragma unroll
    for (int gi = 0; gi < 12; gi++){
      int c = c0 + gi*4;
      if (c < 180){
        f32x4 gg = *(const f32x4*)(g1 + c);
        f32x4 bb = *(const f32x4*)(be1 + c);
        float v0 = (bf2f((ushort_t)(mv[gi]    )) - mu)*rstd*gg.x + bb.x;
        float v1 = (bf2f((ushort_t)(mv[gi]>>16)) - mu)*rstd*gg.y + bb.y;
        float v2 = (bf2f((ushort_t)(mv[gi]>>32)) - mu)*rstd*gg.z + bb.z;
        float v3 = (bf2f((ushort_t)(mv[gi]>>48)) - mu)*rstd*gg.w + bb.w;
        *(u64*)(hn + row*SH + c) = pack4(v0, v1, v2, v3);
      }
    }
  }
  __syncthreads();

  // ---- attention (R7, unchanged): 12 jobs, 3 per wave; per-wave scratch in W
  {
    ushort_t* buf0 = W + wave*(2*32*SS);   // q, then vT
    ushort_t* buf1 = buf0 + 32*SS;         // k, then P
    const float scl = 0.18257418583505537f;  // 30^-0.5

    #pragma unroll 1
    for (int jj = 0; jj < 3; jj++){
      int j = wave*3 + jj;
      int bb = (j >= 6) ? 1 : 0;
      int head = j - 6*bb;
      const ushort_t* wbase = wqkv + head*(96*192);

      f32x4 accq[2][2], acck[2][2], accv[2][2];
      #pragma unroll
      for (int i = 0; i < 2; i++)
        #pragma unroll
        for (int jx = 0; jx < 2; jx++){ accq[i][jx]=(f32x4)0.f; acck[i][jx]=(f32x4)0.f; accv[i][jx]=(f32x4)0.f; }

      #pragma unroll 1
      for (int kk = 0; kk < 6; kk++){
        const ushort_t* wk0 = wbase + c16*192 + kk*32 + quad*8;
        short8 aq0 = *(const short8*)(wk0);
        short8 aq1 = *(const short8*)(wk0 + 16*192);
        short8 ak0 = *(const short8*)(wk0 + 32*192);
        short8 ak1 = *(const short8*)(wk0 + 48*192);
        short8 av0 = *(const short8*)(wk0 + 64*192);
        short8 av1 = *(const short8*)(wk0 + 80*192);
        const ushort_t* hb = hn + (bb*32 + c16)*SH + kk*32 + quad*8;
        short8 hf0 = *(const short8*)(hb);
        short8 hf1 = *(const short8*)(hb + 16*SH);
        accq[0][0] = MFMA16(aq0, hf0, accq[0][0]);
        accq[0][1] = MFMA16(aq0, hf1, accq[0][1]);
        accq[1][0] = MFMA16(aq1, hf0, accq[1][0]);
        accq[1][1] = MFMA16(aq1, hf1, accq[1][1]);
        acck[0][0] = MFMA16(ak0, hf0, acck[0][0]);
        acck[0][1] = MFMA16(ak0, hf1, acck[0][1]);
        acck[1][0] = MFMA16(ak1, hf0, acck[1][0]);
        acck[1][1] = MFMA16(ak1, hf1, acck[1][1]);
        accv[0][0] = MFMA16(hf0, av0, accv[0][0]);
        accv[0][1] = MFMA16(hf0, av1, accv[0][1]);
        accv[1][0] = MFMA16(hf1, av0, accv[1][0]);
        accv[1][1] = MFMA16(hf1, av1, accv[1][1]);
      }
      #pragma unroll
      for (int mt = 0; mt < 2; mt++)
        #pragma unroll
        for (int nt = 0; nt < 2; nt++){
          *(u64*)(buf0 + (nt*16 + c16)*SS + mt*16 + quad*4) =
            pack4(accq[mt][nt][0], accq[mt][nt][1], accq[mt][nt][2], accq[mt][nt][3]);
          *(u64*)(buf1 + (nt*16 + c16)*SS + mt*16 + quad*4) =
            pack4(acck[mt][nt][0], acck[mt][nt][1], acck[mt][nt][2], acck[mt][nt][3]);
        }
      f32x4 sacc[2][2];
      #pragma unroll
      for (int i = 0; i < 2; i++){ sacc[i][0]=(f32x4)0.f; sacc[i][1]=(f32x4)0.f; }
      short8 akf[2], bqf[2];
      #pragma unroll
      for (int mt = 0; mt < 2; mt++) akf[mt] = *(const short8*)(buf1 + (mt*16 + c16)*SS + quad*8);
      #pragma unroll
      for (int nt = 0; nt < 2; nt++) bqf[nt] = *(const short8*)(buf0 + (nt*16 + c16)*SS + quad*8);
      #pragma unroll
      for (int mt = 0; mt < 2; mt++)
        #pragma unroll
        for (int nt = 0; nt < 2; nt++)
          sacc[mt][nt] = MFMA16(akf[mt], bqf[nt], sacc[mt][nt]);
      #pragma unroll
      for (int nt = 0; nt < 2; nt++){
        int t = nt*16 + c16;
        float v[8];
        #pragma unroll
        for (int r = 0; r < 4; r++){
          int s0 = quad*4 + r, s1v = 16 + quad*4 + r;
          v[r]   = (s0  > t) ? -1e30f : sacc[0][nt][r]*scl;
          v[4+r] = (s1v > t) ? -1e30f : sacc[1][nt][r]*scl;
        }
        float m = v[0];
        #pragma unroll
        for (int i = 1; i < 8; i++) m = fmaxf(m, v[i]);
        m = fmaxf(m, __shfl_xor(m, 16));
        m = fmaxf(m, __shfl_xor(m, 32));
        float e[8], s = 0.f;
        #pragma unroll
        for (int i = 0; i < 8; i++){ e[i] = __expf(v[i] - m); s += e[i]; }
        s += __shfl_xor(s, 16);
        s += __shfl_xor(s, 32);
        float inv = 1.f / s;
        *(u64*)(buf1 + t*SS +      quad*4) = pack4(e[0]*inv, e[1]*inv, e[2]*inv, e[3]*inv);
        *(u64*)(buf1 + t*SS + 16 + quad*4) = pack4(e[4]*inv, e[5]*inv, e[6]*inv, e[7]*inv);
      }
      #pragma unroll
      for (int mt = 0; mt < 2; mt++)
        #pragma unroll
        for (int nt = 0; nt < 2; nt++)
          *(u64*)(buf0 + (nt*16 + c16)*SS + mt*16 + quad*4) =
            pack4(accv[mt][nt][0], accv[mt][nt][1], accv[mt][nt][2], accv[mt][nt][3]);
      f32x4 oacc[2][2];
      #pragma unroll
      for (int i = 0; i < 2; i++){ oacc[i][0]=(f32x4)0.f; oacc[i][1]=(f32x4)0.f; }
      short8 avf[2], bpf[2];
      #pragma unroll
      for (int mt = 0; mt < 2; mt++) avf[mt] = *(const short8*)(buf0 + (mt*16 + c16)*SS + quad*8);
      #pragma unroll
      for (int nt = 0; nt < 2; nt++) bpf[nt] = *(const short8*)(buf1 + (nt*16 + c16)*SS + quad*8);
      #pragma unroll
      for (int mt = 0; mt < 2; mt++)
        #pragma unroll
        for (int nt = 0; nt < 2; nt++)
          oacc[mt][nt] = MFMA16(avf[mt], bpf[nt], oacc[mt][nt]);
      #pragma unroll
      for (int mt = 0; mt < 2; mt++)
        #pragma unroll
        for (int nt = 0; nt < 2; nt++){
          int t = bb*32 + nt*16 + c16;
          int c = head*30 + mt*16 + quad*4;
          ushort_t* p = attU + t*SA + c;
          *(u32*)(p) = pack2(oacc[mt][nt][0], oacc[mt][nt][1]);
          if (mt == 0 || quad < 3)
            *(u32*)(p + 2) = pack2(oacc[mt][nt][2], oacc[mt][nt][3]);
        }
    }
  }
  __syncthreads();

  // ---- x2 = x + att: fp32 -> out (coalesced), bf16 -> hn
  #pragma unroll 1
  for (int it = 0; it < 12; it++){
    int idx = it*256 + tid;
    if (idx < 2880){
      f32x4 v = *(const f32x4*)(x + base + (long)idx*4);
      int row = (int)(((u32)idx * 745655u) >> 25);
      int col4 = (idx - row*45)*4;
      u64 m = *(const u64*)(attU + row*SA + col4);
      v.x += bf2f((ushort_t)(m      ));
      v.y += bf2f((ushort_t)(m >> 16));
      v.z += bf2f((ushort_t)(m >> 32));
      v.w += bf2f((ushort_t)(m >> 48));
      *(f32x4*)(out + base + (long)idx*4) = v;
      *(u64*)(hn + row*SH + col4) = pack4(v.x, v.y, v.z, v.w);
    }
  }
  __syncthreads();   // att region now dead -> bufS

  // ---- LN2 in-place on hn ; prologue-stage first weight slice meanwhile
  {
    int row = tid >> 2, sub = tid & 3;
    int c0 = sub*48;
    float s1 = 0.f, s2 = 0.f;
    u64 mv[12];
    #pragma unroll
    for (int gi = 0; gi < 12; gi++){
      mv[gi] = *(const u64*)(hn + row*SH + c0 + gi*4);
      #pragma unroll
      for (int e = 0; e < 4; e++){
        float v = bf2f((ushort_t)(mv[gi] >> (16*e)));
        s1 += v; s2 += v*v;
      }
    }
    STAGE(w1s, attU);   // slice (ch0,kk0) -> bufS0 ; drained by next __syncthreads
    s1 = red4_add(s1); s2 = red4_add(s2);
    float mu = s1 * (1.f/180.f);
    float rstd = rsqrtf(s2 * (1.f/180.f) - mu*mu + 1e-5f);
    #pragma unroll
    for (int gi = 0; gi < 12; gi++){
      int c = c0 + gi*4;
      if (c < 180){
        f32x4 gg = *(const f32x4*)(g2 + c);
        f32x4 bb = *(const f32x4*)(be2 + c);
        float v0 = (bf2f((ushort_t)(mv[gi]    )) - mu)*rstd*gg.x + bb.x;
        float v1 = (bf2f((ushort_t)(mv[gi]>>16)) - mu)*rstd*gg.y + bb.y;
        float v2 = (bf2f((ushort_t)(mv[gi]>>32)) - mu)*rstd*gg.z + bb.z;
        float v3 = (bf2f((ushort_t)(mv[gi]>>48)) - mu)*rstd*gg.w + bb.w;
        *(u64*)(hn + row*SH + c) = pack4(v0, v1, v2, v3);
      }
    }
  }
  __syncthreads();

  // ---- MLP: 4 chunks; weights streamed slice-by-slice via gll double buffer.
  // Each wave reads only its own quarter of each slice -> kk loops barrier-free.
  {
    ushort_t* act = W;
    ushort_t* bufS0 = attU;
    ushort_t* bufS1 = attU + 6144;
    int cur = 0;
    f32x4 outacc[4][3];
    #pragma unroll
    for (int i = 0; i < 4; i++)
      #pragma unroll
      for (int jx = 0; jx < 3; jx++) outacc[i][jx] = (f32x4)0.f;

    #pragma unroll 1
    for (int ch = 0; ch < 4; ch++){
      f32x4 aacc[3][4];
      #pragma unroll
      for (int i = 0; i < 3; i++)
        #pragma unroll
        for (int jx = 0; jx < 4; jx++) aacc[i][jx] = (f32x4)0.f;

      // MLP1: C[n][t] ; slice(ch,kk) in bufS[cur], stage slice kk+1 (or w2 kk0)
      #pragma unroll 1
      for (int kk = 0; kk < 6; kk++){
        {
          const ushort_t* nsrc = (kk < 5) ? (w1s + (ch*6 + kk + 1)*6144)
                                          : (w2s + (ch*6)*6144);
          STAGE(nsrc, cur ? bufS0 : bufS1);
        }
        WVM(3);
        const ushort_t* wf = (cur ? bufS1 : bufS0) + wave*1536 + quad*128 + c16*8;
        short8 aw0 = *(const short8*)(wf);
        short8 aw1 = *(const short8*)(wf + 512);
        short8 aw2 = *(const short8*)(wf + 1024);
        const ushort_t* hb = hn + c16*SH + kk*32 + quad*8;
        short8 bh0 = *(const short8*)(hb);
        short8 bh1 = *(const short8*)(hb + 16*SH);
        short8 bh2 = *(const short8*)(hb + 32*SH);
        short8 bh3 = *(const short8*)(hb + 48*SH);
        __builtin_amdgcn_s_setprio(1);
        aacc[0][0] = MFMA16(aw0, bh0, aacc[0][0]);
        aacc[0][1] = MFMA16(aw0, bh1, aacc[0][1]);
        aacc[0][2] = MFMA16(aw0, bh2, aacc[0][2]);
        aacc[0][3] = MFMA16(aw0, bh3, aacc[0][3]);
        aacc[1][0] = MFMA16(aw1, bh0, aacc[1][0]);
        aacc[1][1] = MFMA16(aw1, bh1, aacc[1][1]);
        aacc[1][2] = MFMA16(aw1, bh2, aacc[1][2]);
        aacc[1][3] = MFMA16(aw1, bh3, aacc[1][3]);
        aacc[2][0] = MFMA16(aw2, bh0, aacc[2][0]);
        aacc[2][1] = MFMA16(aw2, bh1, aacc[2][1]);
        aacc[2][2] = MFMA16(aw2, bh2, aacc[2][2]);
        aacc[2][3] = MFMA16(aw2, bh3, aacc[2][3]);
        __builtin_amdgcn_s_setprio(0);
        cur ^= 1;
      }
      // bias + relu + act store (bias from LDS: no vmem here)
      #pragma unroll
      for (int mi = 0; mi < 3; mi++){
        int nrel = (wave*3+mi)*16 + quad*4;
        int nabs = ch*192 + nrel;
        f32x4 bias = (f32x4)0.f;
        if (nabs < 720) bias = *(const f32x4*)(biasL + nabs);
        #pragma unroll
        for (int tt = 0; tt < 4; tt++){
          float v0 = fmaxf(aacc[mi][tt][0] + bias[0], 0.f);
          float v1 = fmaxf(aacc[mi][tt][1] + bias[1], 0.f);
          float v2 = fmaxf(aacc[mi][tt][2] + bias[2], 0.f);
          float v3 = fmaxf(aacc[mi][tt][3] + bias[3], 0.f);
          *(u64*)(act + (tt*16 + c16)*SH + nrel) = pack4(v0, v1, v2, v3);
        }
      }
      __syncthreads();   // publish act (also drains in-flight stage; restaged cheaply from L2)
      // MLP2: C[t][no]
      #pragma unroll 1
      for (int kk = 0; kk < 6; kk++){
        if (ch == 3 && kk == 5){
          WVM(0);
        } else {
          {
            const ushort_t* nsrc = (kk < 5) ? (w2s + (ch*6 + kk + 1)*6144)
                                            : (w1s + ((ch+1)*6)*6144);
            STAGE(nsrc, cur ? bufS0 : bufS1);
          }
          WVM(3);
        }
        const ushort_t* wf = (cur ? bufS1 : bufS0) + wave*1536 + quad*128 + c16*8;
        short8 bw0 = *(const short8*)(wf);
        short8 bw1 = *(const short8*)(wf + 512);
        short8 bw2 = *(const short8*)(wf + 1024);
        const ushort_t* ab = act + c16*SH + kk*32 + quad*8;
        short8 aa0 = *(const short8*)(ab);
        short8 aa1 = *(const short8*)(ab + 16*SH);
        short8 aa2 = *(const short8*)(ab + 32*SH);
        short8 aa3 = *(const short8*)(ab + 48*SH);
        __builtin_amdgcn_s_setprio(1);
        outacc[0][0] = MFMA16(aa0, bw0, outacc[0][0]);
        outacc[0][1] = MFMA16(aa0, bw1, outacc[0][1]);
        outacc[0][2] = MFMA16(aa0, bw2, outacc[0][2]);
        outacc[1][0] = MFMA16(aa1, bw0, outacc[1][0]);
        outacc[1][1] = MFMA16(aa1, bw1, outacc[1][1]);
        outacc[1][2] = MFMA16(aa1, bw2, outacc[1][2]);
        outacc[2][0] = MFMA16(aa2, bw0, outacc[2][0]);
        outacc[2][1] = MFMA16(aa2, bw1, outacc[2][1]);
        outacc[2][2] = MFMA16(aa2, bw2, outacc[2][2]);
        outacc[3][0] = MFMA16(aa3, bw0, outacc[3][0]);
        outacc[3][1] = MFMA16(aa3, bw1, outacc[3][1]);
        outacc[3][2] = MFMA16(aa3, bw2, outacc[3][2]);
        __builtin_amdgcn_s_setprio(0);
        cur ^= 1;
      }
      if (ch < 3) __syncthreads();   // all waves done reading act before next overwrite
    }
    // epilogue: out[t][no] = x2 (already in out) + mlp + b2
    #pragma unroll
    for (int ntl = 0; ntl < 3; ntl++){
      int no = wave*48 + ntl*16 + c16;
      if (no < 180){
        float bias = b2[no];
        #pragma unroll
        for (int tt = 0; tt < 4; tt++){
          #pragma unroll
          for (int r = 0; r < 4; r++){
            long a = base + (long)(tt*16 + quad*4 + r)*180 + no;
            out[a] = out[a] + outacc[tt][ntl][r] + bias;
          }
        }
      }
    }
  }
}

extern "C" void kernel_launch(void* const* d_in, const int* in_sizes, int n_in,
                              void* d_out, int out_size, void* d_ws, size_t ws_size,
                              hipStream_t stream) {
  const float* x   = (const float*)d_in[0];
  const float* wq  = (const float*)d_in[1];
  const float* wk  = (const float*)d_in[2];
  const float* wv  = (const float*)d_in[3];
  const float* g1  = (const float*)d_in[4];
  const float* be1 = (const float*)d_in[5];
  const float* g2  = (const float*)d_in[6];
  const float* be2 = (const float*)d_in[7];
  const float* w1  = (const float*)d_in[8];
  const float* b1  = (const float*)d_in[9];
  const float* w2  = (const float*)d_in[10];
  const float* b2  = (const float*)d_in[11];
  ushort_t* ws   = (ushort_t*)d_ws;
  ushort_t* wqkv = ws;
  ushort_t* w1s  = ws + WQKV_ELEMS;
  ushort_t* w2s  = w1s + W1T_ELEMS;
  float* out = (float*)d_out;

  prep_weights<<<512, 256, 0, stream>>>(wq, wk, wv, w1, w2, ws);
  block_kernel<<<2048, 256, 0, stream>>>(x, g1, be1, g2, be2, b1, b2,
                                         wqkv, w1s, w2s, out);
}